// Round 2
// baseline (2598.876 us; speedup 1.0000x reference)
//
#include <hip/hip_runtime.h>
#include <hip/hip_bf16.h>

#define NN 50000
#define NE 100000
#define D 40
#define DE 10
#define DH 128
#define DD 1600  // D*D

typedef __bf16 bf16;
typedef bf16 bf16x8 __attribute__((ext_vector_type(8)));
typedef float f32x4 __attribute__((ext_vector_type(4)));

__global__ __launch_bounds__(256) void k_zero(float* __restrict__ p, int n) {
    int t = blockIdx.x * 256 + threadIdx.x;
    if (t < n) p[t] = 0.f;
}

// r = relu(e_feat @ e1_w + e1_b) -> bf16 (E x 128)
__global__ __launch_bounds__(256) void k_edge1(const float* __restrict__ ef,
                                               const float* __restrict__ w,
                                               const float* __restrict__ b,
                                               bf16* __restrict__ r) {
    int t = blockIdx.x * 256 + threadIdx.x;  // E*128 threads, exact
    int h = t & 127, e = t >> 7;
    float acc = b[h];
    const float* efe = ef + e * DE;
#pragma unroll
    for (int d = 0; d < DE; ++d) acc += efe[d] * w[d * DH + h];
    r[t] = (bf16)fmaxf(acc, 0.f);
}

// transpose-convert e2_w (128x1600 f32) -> Bt (1600x128 bf16)
__global__ __launch_bounds__(256) void k_cvtB(const float* __restrict__ w,
                                              bf16* __restrict__ bt) {
    int t = blockIdx.x * 256 + threadIdx.x;  // 1600*128 threads, exact
    int k = t & 127, n = t >> 7;
    bt[t] = (bf16)w[k * DD + n];
}

// W[el, col] = r[ebase+el,:] @ e2_w[:,col] + e2_b[col], bf16 (chunk-local W)
__global__ __launch_bounds__(256) void k_gemm2(const bf16* __restrict__ r,
                                               const bf16* __restrict__ bt,
                                               const float* __restrict__ e2b,
                                               bf16* __restrict__ W, int ebase) {
    int wave = threadIdx.x >> 6;
    int lane = threadIdx.x & 63;
    int el0 = blockIdx.x * 16;  // chunk-local edge base for this block
    int row = lane & 15;        // A-row / B-col / D-col
    int kg = lane >> 4;         // k-group (0..3)
    bf16x8 a[4];
    const bf16* rp = r + (size_t)(ebase + el0 + row) * DH + kg * 8;
#pragma unroll
    for (int s = 0; s < 4; ++s) a[s] = *(const bf16x8*)(rp + s * 32);
    for (int nt = wave; nt < 100; nt += 4) {
        int n0 = nt * 16;
        f32x4 acc = {0.f, 0.f, 0.f, 0.f};
        const bf16* bp = bt + (size_t)(n0 + row) * DH + kg * 8;
#pragma unroll
        for (int s = 0; s < 4; ++s) {
            bf16x8 bfrag = *(const bf16x8*)(bp + s * 32);
            acc = __builtin_amdgcn_mfma_f32_16x16x32_bf16(a[s], bfrag, acc, 0, 0, 0);
        }
        int col = n0 + row;          // D: col = lane & 15
        float bias = e2b[col];
        int er = el0 + kg * 4;       // D: row = (lane>>4)*4 + reg
#pragma unroll
        for (int q = 0; q < 4; ++q)
            W[(size_t)(er + q) * DD + col] = (bf16)(acc[q] + bias);
    }
}

// out0 = relu(n_feat @ lin0_w + lin0_b)
__global__ __launch_bounds__(256) void k_lin0(const float* __restrict__ nf,
                                              const float* __restrict__ w,
                                              const float* __restrict__ b,
                                              float* __restrict__ out) {
    int t = blockIdx.x * 256 + threadIdx.x;
    if (t >= NN * D) return;
    int o = t % D, n = t / D;
    float acc = b[o];
    const float* x = nf + n * D;
#pragma unroll
    for (int d = 0; d < D; ++d) acc += x[d] * w[d * D + o];
    out[t] = fmaxf(acc, 0.f);
}

// per-edge matvec msg = x_src @ W_e (chunk-local W), scatter-add into agg
__global__ __launch_bounds__(256) void k_msg(const float* __restrict__ out,
                                             const bf16* __restrict__ W,
                                             const int* __restrict__ src,
                                             const int* __restrict__ dst,
                                             float* __restrict__ agg, int ebase) {
    __shared__ float xs[4][D];
    int wave = threadIdx.x >> 6, lane = threadIdx.x & 63;
    int el = blockIdx.x * 4 + wave;  // chunk-local
    int e = ebase + el;
    int s = src[e];
    if (lane < D) xs[wave][lane] = out[s * D + lane];
    __syncthreads();
    if (lane < D) {
        const bf16* We = W + (size_t)el * DD;
        float acc = 0.f;
#pragma unroll
        for (int d = 0; d < D; ++d) acc += xs[wave][d] * (float)We[d * D + lane];
        atomicAdd(&agg[dst[e] * D + lane], acc);
    }
}

// node update: m = relu(agg + out@res_w + conv_b); out' = [m,out]@msg_w + msg_b (+ n_feat if LAST)
template <int LAST>
__global__ __launch_bounds__(256) void k_node(const float* __restrict__ out,
                                              const float* __restrict__ agg,
                                              const float* __restrict__ res_w,
                                              const float* __restrict__ conv_b,
                                              const float* __restrict__ msg_w,
                                              const float* __restrict__ msg_b,
                                              const float* __restrict__ nf,
                                              float* __restrict__ out_new) {
    __shared__ float xs[6][D], ms[6][D];
    int ni = threadIdx.x / D, o = threadIdx.x % D;
    int n = blockIdx.x * 6 + ni;
    bool ok = (ni < 6) && (n < NN);
    if (ok) xs[ni][o] = out[n * D + o];
    __syncthreads();
    if (ok) {
        float t = conv_b[o] + agg[n * D + o];
#pragma unroll
        for (int d = 0; d < D; ++d) t += xs[ni][d] * res_w[d * D + o];
        ms[ni][o] = fmaxf(t, 0.f);
    }
    __syncthreads();
    if (ok) {
        float acc = msg_b[o];
#pragma unroll
        for (int d = 0; d < D; ++d)
            acc += ms[ni][d] * msg_w[d * D + o] + xs[ni][d] * msg_w[(D + d) * D + o];
        if (LAST) acc += nf[n * D + o];
        out_new[n * D + o] = acc;
    }
}

extern "C" void kernel_launch(void* const* d_in, const int* in_sizes, int n_in,
                              void* d_out, int out_size, void* d_ws, size_t ws_size,
                              hipStream_t stream) {
    const float* n_feat = (const float*)d_in[0];
    const float* e_feat = (const float*)d_in[1];
    const int* src = (const int*)d_in[2];
    const int* dst = (const int*)d_in[3];
    const float* lin0_w = (const float*)d_in[4];
    const float* lin0_b = (const float*)d_in[5];
    const float* msg_w = (const float*)d_in[6];
    const float* msg_b = (const float*)d_in[7];
    const float* e1_w = (const float*)d_in[8];
    const float* e1_b = (const float*)d_in[9];
    const float* e2_w = (const float*)d_in[10];
    const float* e2_b = (const float*)d_in[11];
    const float* res_w = (const float*)d_in[12];
    const float* conv_b = (const float*)d_in[13];
    float* outF = (float*)d_out;

    // Fixed buffers first, then the W slab sized to whatever remains.
    char* p = (char*)d_ws;
    bf16* r = (bf16*)p;      p += (size_t)NE * DH * 2;   // 25.6 MB
    bf16* Bt = (bf16*)p;     p += (size_t)DD * DH * 2;   // 0.41 MB
    float* outA = (float*)p; p += (size_t)NN * D * 4;    // 8 MB
    float* outB = (float*)p; p += (size_t)NN * D * 4;    // 8 MB
    float* agg = (float*)p;  p += (size_t)NN * D * 4;    // 8 MB
    size_t used = (size_t)(p - (char*)d_ws);
    size_t wcap = (ws_size > used) ? (ws_size - used) : 0;
    bf16* W = (bf16*)p;

    // Largest chunk (divides NE, multiple of 16) whose W slab fits remaining ws.
    const int opts[6] = {100000, 50000, 20000, 10000, 4000, 2000};
    int chunk = 2000;
    for (int i = 0; i < 6; ++i) {
        if ((size_t)opts[i] * DD * 2 <= wcap) { chunk = opts[i]; break; }
    }

    // edge-network hidden + weight transpose + node init (once)
    k_edge1<<<(NE * DH) / 256, 256, 0, stream>>>(e_feat, e1_w, e1_b, r);
    k_cvtB<<<(DD * DH) / 256, 256, 0, stream>>>(e2_w, Bt);
    k_lin0<<<(NN * D + 255) / 256, 256, 0, stream>>>(n_feat, lin0_w, lin0_b, outA);
    if (chunk == NE) {
        k_gemm2<<<NE / 16, 256, 0, stream>>>(r, Bt, e2_b, W, 0);
    }

    float* cur = outA;
    float* nxt = outB;
    for (int s = 0; s < 6; ++s) {
        k_zero<<<(NN * D + 255) / 256, 256, 0, stream>>>(agg, NN * D);
        if (chunk == NE) {
            k_msg<<<NE / 4, 256, 0, stream>>>(cur, W, src, dst, agg, 0);
        } else {
            for (int eb = 0; eb < NE; eb += chunk) {
                k_gemm2<<<chunk / 16, 256, 0, stream>>>(r, Bt, e2_b, W, eb);
                k_msg<<<chunk / 4, 256, 0, stream>>>(cur, W, src, dst, agg, eb);
            }
        }
        if (s == 5) {
            k_node<1><<<(NN + 5) / 6, 256, 0, stream>>>(cur, agg, res_w, conv_b,
                                                        msg_w, msg_b, n_feat, outF);
        } else {
            k_node<0><<<(NN + 5) / 6, 256, 0, stream>>>(cur, agg, res_w, conv_b,
                                                        msg_w, msg_b, n_feat, nxt);
            float* t = cur; cur = nxt; nxt = t;
        }
    }
}

// Round 5
// 1363.069 us; speedup vs baseline: 1.9066x; 1.9066x over previous
//
#include <hip/hip_runtime.h>
#include <hip/hip_bf16.h>

#define NN 50000
#define NE 100000
#define D 40
#define DE 10
#define DH 128
#define DD 1600  // D*D

typedef __bf16 bf16;
typedef bf16 bf16x8 __attribute__((ext_vector_type(8)));
typedef bf16 bf16x4 __attribute__((ext_vector_type(4)));
typedef float f32x4 __attribute__((ext_vector_type(4)));

__global__ __launch_bounds__(256) void k_zero(float* __restrict__ p, int n) {
    int t = blockIdx.x * 256 + threadIdx.x;
    if (t < n) p[t] = 0.f;
}

// r = relu(e_feat @ e1_w + e1_b) -> bf16 (E x 128)
__global__ __launch_bounds__(256) void k_edge1(const float* __restrict__ ef,
                                               const float* __restrict__ w,
                                               const float* __restrict__ b,
                                               bf16* __restrict__ r) {
    int t = blockIdx.x * 256 + threadIdx.x;  // E*128 threads, exact
    int h = t & 127, e = t >> 7;
    float acc = b[h];
    const float* efe = ef + e * DE;
#pragma unroll
    for (int d = 0; d < DE; ++d) acc += efe[d] * w[d * DH + h];
    r[t] = (bf16)fmaxf(acc, 0.f);
}

// BtP[j'][k] = e2_w[k][j] with j = d*40+o, j' = o*40+d  (permuted transpose, bf16)
__global__ __launch_bounds__(256) void k_cvtB(const float* __restrict__ w,
                                              bf16* __restrict__ btp) {
    int t = blockIdx.x * 256 + threadIdx.x;  // DD*DH threads, exact
    int k = t & 127, jp = t >> 7;
    int o = jp / D, d = jp % D;
    btp[t] = (bf16)w[k * DD + d * D + o];
}

// biasP[j'] = e2_b[d*40+o]
__global__ __launch_bounds__(256) void k_cvtBias(const float* __restrict__ b,
                                                 float* __restrict__ bp) {
    int t = blockIdx.x * 256 + threadIdx.x;
    if (t >= DD) return;
    int o = t / D, d = t % D;
    bp[t] = b[d * D + o];
}

// Persisted edge-weight GEMM, permuted-transposed output:
// WT[e][j'=o*40+d] = r[e,:] @ BtP[j',:] + biasP[j']  -- bf16x4 stores.
// A = BtP (M=j'), B = r (N=16 edges). D: col(lane&15)=edge, row(kg*4+q)=j'.
__global__ __launch_bounds__(256) void k_gemm2T(const bf16* __restrict__ r,
                                                const bf16* __restrict__ btp,
                                                const float* __restrict__ biasp,
                                                bf16* __restrict__ WT) {
    int wave = threadIdx.x >> 6, lane = threadIdx.x & 63;
    int r15 = lane & 15, kg = lane >> 4;
    int e0 = blockIdx.x * 16;
    bf16x8 b[4];
    const bf16* rp = r + (size_t)(e0 + r15) * DH + kg * 8;
#pragma unroll
    for (int s = 0; s < 4; ++s) b[s] = *(const bf16x8*)(rp + s * 32);
    for (int nt = wave; nt < 100; nt += 4) {
        int j0 = nt * 16;
        f32x4 acc = {0.f, 0.f, 0.f, 0.f};
        const bf16* ap = btp + (size_t)(j0 + r15) * DH + kg * 8;
#pragma unroll
        for (int s = 0; s < 4; ++s)
            acc = __builtin_amdgcn_mfma_f32_16x16x32_bf16(*(const bf16x8*)(ap + s * 32),
                                                          b[s], acc, 0, 0, 0);
        int jb = j0 + kg * 4;
        f32x4 bias = *(const f32x4*)(biasp + jb);
        bf16x4 ov;
#pragma unroll
        for (int q = 0; q < 4; ++q) ov[q] = (bf16)(acc[q] + bias[q]);
        *(bf16x4*)(WT + (size_t)(e0 + r15) * DD + jb) = ov;
    }
}

// out0 = relu(n_feat @ lin0_w + lin0_b)
__global__ __launch_bounds__(256) void k_lin0(const float* __restrict__ nf,
                                              const float* __restrict__ w,
                                              const float* __restrict__ b,
                                              float* __restrict__ out) {
    int t = blockIdx.x * 256 + threadIdx.x;
    if (t >= NN * D) return;
    int o = t % D, n = t / D;
    float acc = b[o];
    const float* x = nf + n * D;
#pragma unroll
    for (int d = 0; d < D; ++d) acc += x[d] * w[d * D + o];
    out[t] = fmaxf(acc, 0.f);
}

// Message pass over persisted edges: msg[e][o] = sum_d x_src[d] * WT[e][o*40+d]
// block = 320 threads = 8 edges x 40 outs; contiguous 80B W-row per thread.
__global__ __launch_bounds__(320) void k_msgP(const float* __restrict__ x,
                                              const bf16* __restrict__ WT,
                                              const int* __restrict__ src,
                                              const int* __restrict__ dst,
                                              float* __restrict__ agg) {
    __shared__ float xs[8][D];
    __shared__ int ss[8], dd[8];
    int tid = threadIdx.x;
    int el0 = blockIdx.x * 8;
    if (tid < 8) { ss[tid] = src[el0 + tid]; dd[tid] = dst[el0 + tid]; }
    __syncthreads();
    int e_l = tid / D, o = tid % D;
    xs[e_l][o] = x[ss[e_l] * D + o];
    __syncthreads();
    const bf16* wp = WT + (size_t)(el0 + e_l) * DD + o * D;
    const float* xr = xs[e_l];
    float acc = 0.f;
#pragma unroll
    for (int c = 0; c < 5; ++c) {
        bf16x8 w8 = *(const bf16x8*)(wp + c * 8);
#pragma unroll
        for (int j = 0; j < 8; ++j) acc += (float)w8[j] * xr[c * 8 + j];
    }
    atomicAdd(&agg[dd[e_l] * D + o], acc);
}

// Fused edge-weight GEMM + message for non-persisted edges (no W materialization).
// Per block: 16 edges; waves split the 100 j'-tiles.
// NOTE: lanes kg=0..3 with the same r15 can map to the SAME o (o = jb/40
// collapses different kg) -> intra-wave collision. Must use LDS atomicAdd,
// a plain += loses updates across lockstep lanes (Round-4 bug).
__global__ __launch_bounds__(256) void k_fused(const float* __restrict__ x,
                                               const bf16* __restrict__ r,
                                               const bf16* __restrict__ btp,
                                               const float* __restrict__ biasp,
                                               const int* __restrict__ src,
                                               const int* __restrict__ dst,
                                               float* __restrict__ agg, int ebase) {
    __shared__ float xs[16][44];      // padded: 16B-aligned rows, conflict-light
    __shared__ float mb[4][16][42];   // per-wave msg accum, padded
    __shared__ int ss[16], dd[16];
    int tid = threadIdx.x, wave = tid >> 6, lane = tid & 63;
    int r15 = lane & 15, kg = lane >> 4;
    int e0 = ebase + blockIdx.x * 16;
    if (tid < 16) dd[tid] = dst[e0 + tid];
    else if (tid < 32) ss[tid - 16] = src[e0 + tid - 16];
    __syncthreads();
    for (int i = tid; i < 16 * D; i += 256) xs[i / D][i % D] = x[ss[i / D] * D + i % D];
    for (int i = tid; i < 4 * 16 * 42; i += 256) ((float*)mb)[i] = 0.f;
    bf16x8 b[4];
    const bf16* rp = r + (size_t)(e0 + r15) * DH + kg * 8;
#pragma unroll
    for (int s = 0; s < 4; ++s) b[s] = *(const bf16x8*)(rp + s * 32);
    __syncthreads();
    for (int nt = wave; nt < 100; nt += 4) {
        int j0 = nt * 16;
        f32x4 acc = {0.f, 0.f, 0.f, 0.f};
        const bf16* ap = btp + (size_t)(j0 + r15) * DH + kg * 8;
#pragma unroll
        for (int s = 0; s < 4; ++s)
            acc = __builtin_amdgcn_mfma_f32_16x16x32_bf16(*(const bf16x8*)(ap + s * 32),
                                                          b[s], acc, 0, 0, 0);
        int jb = j0 + kg * 4;             // 4-aligned; 40%4==0 -> quad never crosses o
        int o = jb / D, d0 = jb % D;
        f32x4 bias = *(const f32x4*)(biasp + jb);
        f32x4 xq = *(const f32x4*)(&xs[r15][d0]);
        float p = (acc[0] + bias[0]) * xq[0] + (acc[1] + bias[1]) * xq[1] +
                  (acc[2] + bias[2]) * xq[2] + (acc[3] + bias[3]) * xq[3];
        atomicAdd(&mb[wave][r15][o], p);  // kg-lanes may collide on same (r15,o)
    }
    __syncthreads();
    for (int i = tid; i < 16 * D; i += 256) {
        int e_l = i / D, o = i % D;
        float v = mb[0][e_l][o] + mb[1][e_l][o] + mb[2][e_l][o] + mb[3][e_l][o];
        atomicAdd(&agg[dd[e_l] * D + o], v);
    }
}

// node update: m = relu(agg + out@res_w + conv_b); out' = [m,out]@msg_w + msg_b (+ n_feat if LAST)
template <int LAST>
__global__ __launch_bounds__(256) void k_node(const float* __restrict__ out,
                                              const float* __restrict__ agg,
                                              const float* __restrict__ res_w,
                                              const float* __restrict__ conv_b,
                                              const float* __restrict__ msg_w,
                                              const float* __restrict__ msg_b,
                                              const float* __restrict__ nf,
                                              float* __restrict__ out_new) {
    __shared__ float xs[6][D], ms[6][D];
    int ni = threadIdx.x / D, o = threadIdx.x % D;
    int n = blockIdx.x * 6 + ni;
    bool ok = (ni < 6) && (n < NN);
    if (ok) xs[ni][o] = out[n * D + o];
    __syncthreads();
    if (ok) {
        float t = conv_b[o] + agg[n * D + o];
#pragma unroll
        for (int d = 0; d < D; ++d) t += xs[ni][d] * res_w[d * D + o];
        ms[ni][o] = fmaxf(t, 0.f);
    }
    __syncthreads();
    if (ok) {
        float acc = msg_b[o];
#pragma unroll
        for (int d = 0; d < D; ++d)
            acc += ms[ni][d] * msg_w[d * D + o] + xs[ni][d] * msg_w[(D + d) * D + o];
        if (LAST) acc += nf[n * D + o];
        out_new[n * D + o] = acc;
    }
}

extern "C" void kernel_launch(void* const* d_in, const int* in_sizes, int n_in,
                              void* d_out, int out_size, void* d_ws, size_t ws_size,
                              hipStream_t stream) {
    const float* n_feat = (const float*)d_in[0];
    const float* e_feat = (const float*)d_in[1];
    const int* src = (const int*)d_in[2];
    const int* dst = (const int*)d_in[3];
    const float* lin0_w = (const float*)d_in[4];
    const float* lin0_b = (const float*)d_in[5];
    const float* msg_w = (const float*)d_in[6];
    const float* msg_b = (const float*)d_in[7];
    const float* e1_w = (const float*)d_in[8];
    const float* e1_b = (const float*)d_in[9];
    const float* e2_w = (const float*)d_in[10];
    const float* e2_b = (const float*)d_in[11];
    const float* res_w = (const float*)d_in[12];
    const float* conv_b = (const float*)d_in[13];
    float* outF = (float*)d_out;

    char* p = (char*)d_ws;
    bf16* r = (bf16*)p;       p += (size_t)NE * DH * 2;   // 25.6 MB
    bf16* BtP = (bf16*)p;     p += (size_t)DD * DH * 2;   // 0.41 MB
    float* biasP = (float*)p; p += (size_t)DD * 4;        // 6.4 KB
    float* outA = (float*)p;  p += (size_t)NN * D * 4;    // 8 MB
    float* outB = (float*)p;  p += (size_t)NN * D * 4;    // 8 MB
    float* agg = (float*)p;   p += (size_t)NN * D * 4;    // 8 MB
    size_t used = (size_t)(p - (char*)d_ws);
    bf16* WT = (bf16*)p;

    // Persist W for as many edges as fit in the remaining workspace.
    long long wcap = (long long)ws_size - (long long)used;
    long long kmax = wcap > 0 ? wcap / ((long long)DD * 2) : 0;
    int K = kmax >= NE ? NE : (int)kmax;
    K &= ~15;  // multiple of 16
    if (K < 0) K = 0;

    k_edge1<<<(NE * DH) / 256, 256, 0, stream>>>(e_feat, e1_w, e1_b, r);
    k_cvtB<<<(DD * DH) / 256, 256, 0, stream>>>(e2_w, BtP);
    k_cvtBias<<<(DD + 255) / 256, 256, 0, stream>>>(e2_b, biasP);
    k_lin0<<<(NN * D + 255) / 256, 256, 0, stream>>>(n_feat, lin0_w, lin0_b, outA);
    if (K > 0) k_gemm2T<<<K / 16, 256, 0, stream>>>(r, BtP, biasP, WT);

    float* cur = outA;
    float* nxt = outB;
    for (int s = 0; s < 6; ++s) {
        k_zero<<<(NN * D + 255) / 256, 256, 0, stream>>>(agg, NN * D);
        if (K > 0) k_msgP<<<K / 8, 320, 0, stream>>>(cur, WT, src, dst, agg);
        if (K < NE) k_fused<<<(NE - K) / 16, 256, 0, stream>>>(cur, r, BtP, biasP,
                                                               src, dst, agg, K);
        if (s == 5) {
            k_node<1><<<(NN + 5) / 6, 256, 0, stream>>>(cur, agg, res_w, conv_b,
                                                        msg_w, msg_b, n_feat, outF);
        } else {
            k_node<0><<<(NN + 5) / 6, 256, 0, stream>>>(cur, agg, res_w, conv_b,
                                                        msg_w, msg_b, n_feat, nxt);
            float* t = cur; cur = nxt; nxt = t;
        }
    }
}

// Round 9
// 1111.576 us; speedup vs baseline: 2.3380x; 1.2262x over previous
//
// Resubmission (4th attempt) — Rounds 6-8 all failed on container infra
// (UnresponsiveContainer, same dead container); this source has never run.
#include <hip/hip_runtime.h>
#include <hip/hip_bf16.h>

#define NN 50000
#define NE 100000
#define D 40
#define DE 10
#define DH 128
#define DD 1600  // D*D

typedef __bf16 bf16;
typedef bf16 bf16x8 __attribute__((ext_vector_type(8)));
typedef bf16 bf16x4 __attribute__((ext_vector_type(4)));
typedef float f32x4 __attribute__((ext_vector_type(4)));

// Fragment-major layouts (one 16-B chunk per lane, contiguous per wave-load):
//   rF  idx = ((eg*4 + s)*64 + lane)*8 + j  holds r[e=eg*16+(lane&15)][k=(lane>>4)*8+s*32+j]
//   BtF idx = ((nt*4 + s)*64 + lane)*8 + j  holds e2_w[k][d*40+o], j'=nt*16+(lane&15), o=j'/40, d=j'%40

__global__ __launch_bounds__(256) void k_zero(float* __restrict__ p, int n) {
    int t = blockIdx.x * 256 + threadIdx.x;
    if (t < n) p[t] = 0.f;
}

// r (fragment-major) = relu(e_feat @ e1_w + e1_b); thread computes 8 h-values, 16-B store.
__global__ __launch_bounds__(256) void k_edge1(const float* __restrict__ ef,
                                               const float* __restrict__ w,
                                               const float* __restrict__ b,
                                               bf16* __restrict__ rF) {
    int t = blockIdx.x * 256 + threadIdx.x;  // NE*16 threads exact
    int lane = t & 63;
    int e = (t >> 8) * 16 + (lane & 15);
    int kbase = (lane >> 4) * 8 + ((t >> 6) & 3) * 32;
    float efr[DE];
#pragma unroll
    for (int d = 0; d < DE; ++d) efr[d] = ef[e * DE + d];
    bf16x8 ov;
#pragma unroll
    for (int j = 0; j < 8; ++j) {
        int h = kbase + j;
        float acc = b[h];
#pragma unroll
        for (int d = 0; d < DE; ++d) acc += efr[d] * w[d * DH + h];
        ov[j] = (bf16)fmaxf(acc, 0.f);
    }
    *(bf16x8*)(rF + (size_t)t * 8) = ov;
}

// BtF fragment-major from e2_w (one-time, tiny)
__global__ __launch_bounds__(256) void k_cvtB(const float* __restrict__ w,
                                              bf16* __restrict__ btf) {
    int t = blockIdx.x * 256 + threadIdx.x;  // 100*4*64 = 25600 threads exact
    int lane = t & 63;
    int jp = (t >> 8) * 16 + (lane & 15);
    int kbase = (lane >> 4) * 8 + ((t >> 6) & 3) * 32;
    int o = jp / D, d = jp % D;
    bf16x8 ov;
#pragma unroll
    for (int j = 0; j < 8; ++j) ov[j] = (bf16)w[(kbase + j) * DD + d * D + o];
    *(bf16x8*)(btf + (size_t)t * 8) = ov;
}

// biasP[j'] = e2_b[d*40+o]
__global__ __launch_bounds__(256) void k_cvtBias(const float* __restrict__ b,
                                                 float* __restrict__ bp) {
    int t = blockIdx.x * 256 + threadIdx.x;
    if (t >= DD) return;
    int o = t / D, d = t % D;
    bp[t] = b[d * D + o];
}

// Persisted edge-weight GEMM: WT[e][j'=o*40+d] row-major via LDS tile + coalesced store.
#define LDP 1640  // padded row (elems): 820 words/row -> 2-way LDS write conflicts (free)
__global__ __launch_bounds__(256) void k_gemm2T(const bf16* __restrict__ rF,
                                                const bf16* __restrict__ btf,
                                                const float* __restrict__ biasp,
                                                bf16* __restrict__ WT) {
    __shared__ bf16 lds[16 * LDP];  // 52.5 KB
    int tid = threadIdx.x, wave = tid >> 6, lane = tid & 63;
    int r15 = lane & 15, kg = lane >> 4;
    int eg = blockIdx.x;
    bf16x8 b[4];
#pragma unroll
    for (int s = 0; s < 4; ++s)
        b[s] = *(const bf16x8*)(rF + (size_t)(((eg * 4 + s) * 64) + lane) * 8);
    for (int nt = wave; nt < 100; nt += 4) {
        f32x4 acc = {0.f, 0.f, 0.f, 0.f};
#pragma unroll
        for (int s = 0; s < 4; ++s) {
            bf16x8 af = *(const bf16x8*)(btf + (size_t)(((nt * 4 + s) * 64) + lane) * 8);
            acc = __builtin_amdgcn_mfma_f32_16x16x32_bf16(af, b[s], acc, 0, 0, 0);
        }
        int jb = nt * 16 + kg * 4;
        f32x4 bias = *(const f32x4*)(biasp + jb);
        bf16x4 ov;
#pragma unroll
        for (int q = 0; q < 4; ++q) ov[q] = (bf16)(acc[q] + bias[q]);
        *(bf16x4*)(lds + r15 * LDP + jb) = ov;
    }
    __syncthreads();
    size_t e0 = (size_t)eg * 16;
    for (int idx = tid; idx < 16 * 200; idx += 256) {  // 16 rows x 200 16-B chunks
        int e = idx / 200, c = idx % 200;
        *(bf16x8*)(WT + (e0 + e) * DD + c * 8) = *(const bf16x8*)(lds + e * LDP + c * 8);
    }
}

// out0 = relu(n_feat @ lin0_w + lin0_b)
__global__ __launch_bounds__(256) void k_lin0(const float* __restrict__ nf,
                                              const float* __restrict__ w,
                                              const float* __restrict__ b,
                                              float* __restrict__ out) {
    int t = blockIdx.x * 256 + threadIdx.x;
    if (t >= NN * D) return;
    int o = t % D, n = t / D;
    float acc = b[o];
    const float* x = nf + n * D;
#pragma unroll
    for (int d = 0; d < D; ++d) acc += x[d] * w[d * D + o];
    out[t] = fmaxf(acc, 0.f);
}

// Message pass over persisted edges; WT rows staged via coalesced loads into LDS.
#define MSP 1608  // padded row elems (16-B aligned)
__global__ __launch_bounds__(320) void k_msgP(const float* __restrict__ x,
                                              const bf16* __restrict__ WT,
                                              const int* __restrict__ src,
                                              const int* __restrict__ dst,
                                              float* __restrict__ agg) {
    __shared__ bf16 w_s[8 * MSP];  // 25.7 KB
    __shared__ float xs[8][D];
    __shared__ int ss[8], dd[8];
    int tid = threadIdx.x;
    int el0 = blockIdx.x * 8;
    if (tid < 8) { ss[tid] = src[el0 + tid]; dd[tid] = dst[el0 + tid]; }
    __syncthreads();
    int e_l = tid / D, o = tid % D;
    xs[e_l][o] = x[ss[e_l] * D + o];
    for (int idx = tid; idx < 8 * 200; idx += 320) {  // 8 rows x 200 16-B chunks
        int e = idx / 200, c = idx % 200;
        *(bf16x8*)(w_s + e * MSP + c * 8) =
            *(const bf16x8*)(WT + (size_t)(el0 + e) * DD + c * 8);
    }
    __syncthreads();
    const bf16* wrow = w_s + e_l * MSP + o * D;
    const float* xr = xs[e_l];
    float acc = 0.f;
#pragma unroll
    for (int c = 0; c < 5; ++c) {
        bf16x8 w8 = *(const bf16x8*)(wrow + c * 8);
#pragma unroll
        for (int j = 0; j < 8; ++j) acc += (float)w8[j] * xr[c * 8 + j];
    }
    atomicAdd(&agg[dd[e_l] * D + o], acc);
}

// Fused edge-weight GEMM + message for non-persisted edges (no W materialization).
// LDS atomicAdd required: kg-lanes can collide on same (r15,o) (Round-4 lesson).
__global__ __launch_bounds__(256) void k_fused(const float* __restrict__ x,
                                               const bf16* __restrict__ rF,
                                               const bf16* __restrict__ btf,
                                               const float* __restrict__ biasp,
                                               const int* __restrict__ src,
                                               const int* __restrict__ dst,
                                               float* __restrict__ agg, int ebase) {
    __shared__ float xs[16][44];
    __shared__ float mb[4][16][42];
    __shared__ int ss[16], dd[16];
    int tid = threadIdx.x, wave = tid >> 6, lane = tid & 63;
    int r15 = lane & 15, kg = lane >> 4;
    int e0 = ebase + blockIdx.x * 16;
    int eg = e0 >> 4;
    if (tid < 16) dd[tid] = dst[e0 + tid];
    else if (tid < 32) ss[tid - 16] = src[e0 + tid - 16];
    __syncthreads();
    for (int i = tid; i < 16 * D; i += 256) xs[i / D][i % D] = x[ss[i / D] * D + i % D];
    for (int i = tid; i < 4 * 16 * 42; i += 256) ((float*)mb)[i] = 0.f;
    bf16x8 b[4];
#pragma unroll
    for (int s = 0; s < 4; ++s)
        b[s] = *(const bf16x8*)(rF + (size_t)(((eg * 4 + s) * 64) + lane) * 8);
    __syncthreads();
    for (int nt = wave; nt < 100; nt += 4) {
        f32x4 acc = {0.f, 0.f, 0.f, 0.f};
#pragma unroll
        for (int s = 0; s < 4; ++s) {
            bf16x8 af = *(const bf16x8*)(btf + (size_t)(((nt * 4 + s) * 64) + lane) * 8);
            acc = __builtin_amdgcn_mfma_f32_16x16x32_bf16(af, b[s], acc, 0, 0, 0);
        }
        int jb = nt * 16 + kg * 4;  // 4-aligned; quad never crosses o (40%4==0)
        int o = jb / D, d0 = jb % D;
        f32x4 bias = *(const f32x4*)(biasp + jb);
        f32x4 xq = *(const f32x4*)(&xs[r15][d0]);
        float p = (acc[0] + bias[0]) * xq[0] + (acc[1] + bias[1]) * xq[1] +
                  (acc[2] + bias[2]) * xq[2] + (acc[3] + bias[3]) * xq[3];
        atomicAdd(&mb[wave][r15][o], p);
    }
    __syncthreads();
    for (int i = tid; i < 16 * D; i += 256) {
        int e_l = i / D, o = i % D;
        float v = mb[0][e_l][o] + mb[1][e_l][o] + mb[2][e_l][o] + mb[3][e_l][o];
        atomicAdd(&agg[dd[e_l] * D + o], v);
    }
}

// node update: m = relu(agg + out@res_w + conv_b); out' = [m,out]@msg_w + msg_b (+ n_feat if LAST)
template <int LAST>
__global__ __launch_bounds__(256) void k_node(const float* __restrict__ out,
                                              const float* __restrict__ agg,
                                              const float* __restrict__ res_w,
                                              const float* __restrict__ conv_b,
                                              const float* __restrict__ msg_w,
                                              const float* __restrict__ msg_b,
                                              const float* __restrict__ nf,
                                              float* __restrict__ out_new) {
    __shared__ float xs[6][D], ms[6][D];
    int ni = threadIdx.x / D, o = threadIdx.x % D;
    int n = blockIdx.x * 6 + ni;
    bool ok = (ni < 6) && (n < NN);
    if (ok) xs[ni][o] = out[n * D + o];
    __syncthreads();
    if (ok) {
        float t = conv_b[o] + agg[n * D + o];
#pragma unroll
        for (int d = 0; d < D; ++d) t += xs[ni][d] * res_w[d * D + o];
        ms[ni][o] = fmaxf(t, 0.f);
    }
    __syncthreads();
    if (ok) {
        float acc = msg_b[o];
#pragma unroll
        for (int d = 0; d < D; ++d)
            acc += ms[ni][d] * msg_w[d * D + o] + xs[ni][d] * msg_w[(D + d) * D + o];
        if (LAST) acc += nf[n * D + o];
        out_new[n * D + o] = acc;
    }
}

extern "C" void kernel_launch(void* const* d_in, const int* in_sizes, int n_in,
                              void* d_out, int out_size, void* d_ws, size_t ws_size,
                              hipStream_t stream) {
    const float* n_feat = (const float*)d_in[0];
    const float* e_feat = (const float*)d_in[1];
    const int* src = (const int*)d_in[2];
    const int* dst = (const int*)d_in[3];
    const float* lin0_w = (const float*)d_in[4];
    const float* lin0_b = (const float*)d_in[5];
    const float* msg_w = (const float*)d_in[6];
    const float* msg_b = (const float*)d_in[7];
    const float* e1_w = (const float*)d_in[8];
    const float* e1_b = (const float*)d_in[9];
    const float* e2_w = (const float*)d_in[10];
    const float* e2_b = (const float*)d_in[11];
    const float* res_w = (const float*)d_in[12];
    const float* conv_b = (const float*)d_in[13];
    float* outF = (float*)d_out;

    char* p = (char*)d_ws;
    bf16* rF = (bf16*)p;      p += (size_t)NE * DH * 2;   // 25.6 MB
    bf16* BtF = (bf16*)p;     p += (size_t)DD * DH * 2;   // 0.41 MB
    float* biasP = (float*)p; p += (size_t)DD * 4;        // 6.4 KB
    float* outA = (float*)p;  p += (size_t)NN * D * 4;    // 8 MB
    float* outB = (float*)p;  p += (size_t)NN * D * 4;    // 8 MB
    float* agg = (float*)p;   p += (size_t)NN * D * 4;    // 8 MB
    size_t used = (size_t)(p - (char*)d_ws);
    bf16* WT = (bf16*)p;

    long long wcap = (long long)ws_size - (long long)used;
    long long kmax = wcap > 0 ? wcap / ((long long)DD * 2) : 0;
    int K = kmax >= NE ? NE : (int)kmax;
    K &= ~15;
    if (K < 0) K = 0;

    k_edge1<<<(NE * 16) / 256, 256, 0, stream>>>(e_feat, e1_w, e1_b, rF);
    k_cvtB<<<(100 * 4 * 64) / 256, 256, 0, stream>>>(e2_w, BtF);
    k_cvtBias<<<(DD + 255) / 256, 256, 0, stream>>>(e2_b, biasP);
    k_lin0<<<(NN * D + 255) / 256, 256, 0, stream>>>(n_feat, lin0_w, lin0_b, outA);
    if (K > 0) k_gemm2T<<<K / 16, 256, 0, stream>>>(rF, BtF, biasP, WT);

    float* cur = outA;
    float* nxt = outB;
    for (int s = 0; s < 6; ++s) {
        k_zero<<<(NN * D + 255) / 256, 256, 0, stream>>>(agg, NN * D);
        if (K > 0) k_msgP<<<K / 8, 320, 0, stream>>>(cur, WT, src, dst, agg);
        if (K < NE) k_fused<<<(NE - K) / 16, 256, 0, stream>>>(cur, rF, BtF, biasP,
                                                               src, dst, agg, K);
        if (s == 5) {
            k_node<1><<<(NN + 5) / 6, 256, 0, stream>>>(cur, agg, res_w, conv_b,
                                                        msg_w, msg_b, n_feat, outF);
        } else {
            k_node<0><<<(NN + 5) / 6, 256, 0, stream>>>(cur, agg, res_w, conv_b,
                                                        msg_w, msg_b, n_feat, nxt);
            float* t = cur; cur = nxt; nxt = t;
        }
    }
}